// Round 7
// baseline (564.217 us; speedup 1.0000x reference)
//
#include <hip/hip_runtime.h>
#include <hip/hip_bf16.h>
#include <stdint.h>

typedef _Float16 half_t;
typedef __attribute__((ext_vector_type(8))) _Float16 half8;
typedef __attribute__((ext_vector_type(4))) _Float16 half4v;
typedef __attribute__((ext_vector_type(4))) float float4v;
typedef unsigned long long u64;

#define D_DIM 768
#define K_CENT 1024
#define M_TOTAL 65536
#define BM 256
#define BN 256
#define BK 32
#define NT 24      /* 768/32 K-tiles */
#define NTN 4      /* 1024/256 n-tiles */

#define BPLANE 16384u  /* one hi or lo plane per chunk: 256 rows x 64 B */

/* ws layout (bytes):
   [0, 1.5MB)     Chi: pre-swizzled f16 hi centroid tiles [n_tile(4)][chunk(24)][16KB]
   [1.5MB, 3MB)   Clo
   [3MB, +4KB)    c2[1024] fp32
   [3MB+8KB,+2MB) partial u64 [65536][4]
   -- big-ws path only --
   [8MiB, +96MiB)   Xhi: pre-swizzled f16 hi X tiles [m_tile(256)][chunk(24)][16KB]
   [104MiB, +96MiB) Xlo                                                     */
#define CLO_OFF  (NTN * NT * BPLANE)   /* 1.5 MB */
#define C2_OFF   (2u * CLO_OFF)        /* 3 MB */
#define PART_OFF (C2_OFF + 8192u)
#define XHI_OFF  8388608u
#define XPLANE   100663296u            /* 65536*768*2 B = 96 MiB */
#define XLO_OFF  (XHI_OFF + XPLANE)
#define WS_NEED  ((size_t)XLO_OFF + (size_t)XPLANE)   /* 200 MiB */

// XOR swizzle for 64B row stride; rows r,r+8 alias 2-way (free). 0 conflicts
// measured in R1/R2.
__device__ __forceinline__ uint32_t swz(uint32_t row, uint32_t kbyte) {
  return (row * 64u + kbyte) ^ (((row >> 1) & 3u) << 4);
}

__device__ __forceinline__ void gll16(const void* g, void* l) {
  __builtin_amdgcn_global_load_lds((const __attribute__((address_space(1))) void*)g,
                                   (__attribute__((address_space(3))) void*)l,
                                   16, 0, 0);
}

#define BAR() __builtin_amdgcn_s_barrier()

// ---------------- kernel 1: centroid split + c2 ----------------
__global__ __launch_bounds__(256) void prep_centroids(const float* __restrict__ cent,
                                                      uint8_t* __restrict__ ws) {
  const int n = blockIdx.x;          // centroid 0..1023
  const int nt = n >> 8, row = n & 255;
  float ss = 0.f;
  for (int d = threadIdx.x; d < D_DIM; d += 256) {
    float a = cent[n * D_DIM + d];
    ss += a * a;
    half_t hi = (half_t)a;
    half_t lo = (half_t)(a - (float)hi);
    int chunk = d >> 5, k = d & 31;
    uint32_t off = (uint32_t)(nt * NT + chunk) * BPLANE + swz((uint32_t)row, (uint32_t)k * 2u);
    *(half_t*)(ws + off) = hi;
    *(half_t*)(ws + CLO_OFF + off) = lo;
  }
  for (int s = 32; s > 0; s >>= 1) ss += __shfl_down(ss, s, 64);
  __shared__ float red[4];
  if ((threadIdx.x & 63) == 0) red[threadIdx.x >> 6] = ss;
  __syncthreads();
  if (threadIdx.x == 0) {
    float* c2 = (float*)(ws + C2_OFF);
    c2[n] = red[0] + red[1] + red[2] + red[3];
  }
}

// ---------------- kernel 1b: X split (big-ws path) ----------------
// One block per (m_tile, chunk): 256 rows x 32 k fp32 -> hi/lo f16 planes,
// pre-swizzled so the GEMM can global_load_lds them linearly.
__global__ __launch_bounds__(256) void prep_x(const float* __restrict__ X,
                                              uint8_t* __restrict__ ws) {
  const uint32_t bid = blockIdx.x;
  const uint32_t mt = bid / 24u, ch = bid % 24u;
  const int tid = threadIdx.x;
  const int row = tid >> 3, c4 = tid & 7;
  const uint32_t pbase = (mt * 24u + ch) * BPLANE;
#pragma unroll
  for (int i = 0; i < 8; ++i) {
    int r = row + i * 32;
    float4v v = *(const float4v*)(X + (size_t)(mt * 256u + r) * D_DIM + ch * 32 + c4 * 4);
    half4v hi, lo;
#pragma unroll
    for (int j = 0; j < 4; ++j) {
      half_t h = (half_t)v[j];
      hi[j] = h;
      lo[j] = (half_t)(v[j] - (float)h);
    }
    uint32_t a = pbase + swz((uint32_t)r, (uint32_t)c4 * 8u);
    *(half4v*)(ws + XHI_OFF + a) = hi;
    *(half4v*)(ws + XLO_OFF + a) = lo;
  }
}

// ================= GEMM variant A: pure-gll (big-ws path) =================
// LDS per buffer c (base c*65536): Ahi@0 Alo@16K Bhi@32K Blo@48K. 128KB total.
// Per K-tile: 3 phases {ds_read ; gll-prefetch ; BAR ; MFMA ; BAR}; zero
// staging VALU; one vmcnt(0) per tile issued >=2 phases after the glls.
__global__ __launch_bounds__(512, 2) void cluster_gemm_gl(const uint8_t* __restrict__ wsro,
                                                          u64* __restrict__ partial) {
  extern __shared__ uint8_t smem[];

  const int bid = blockIdx.x;
  const int L = (bid & 7) * 128 + (bid >> 3);   // bijective XCD swizzle
  const int mt = L >> 2, nt = L & 3;
  const int m0 = mt * BM;

  const int tid = threadIdx.x;
  const int lane = tid & 63, w = tid >> 6;
  const int wm = w >> 2, wn = w & 3;            // 2M x 4N waves; wave tile 128x64
  const uint32_t kb = (uint32_t)((lane >> 4) << 4);

  const float* c2p = (const float*)(wsro + C2_OFF);
  const int ncol = nt * 256 + wn * 64 + (lane & 15);
  float c2v[4];
#pragma unroll
  for (int n = 0; n < 4; ++n) c2v[n] = c2p[ncol + n * 16];

  float4v acc[8][4];
#pragma unroll
  for (int m = 0; m < 8; ++m)
#pragma unroll
    for (int n = 0; n < 4; ++n) acc[m][n] = (float4v){0.f, 0.f, 0.f, 0.f};

  const uint8_t* Ah = wsro + XHI_OFF + (uint32_t)(mt * NT) * BPLANE;
  const uint8_t* Al = wsro + XLO_OFF + (uint32_t)(mt * NT) * BPLANE;
  const uint8_t* Bh = wsro + (uint32_t)(nt * NT) * BPLANE;
  const uint8_t* Bl = wsro + CLO_OFF + (uint32_t)(nt * NT) * BPLANE;
  const uint32_t wo = (uint32_t)w * 2048u;

  half8 ah[4], al[4], bh0[2], bl0[2], bh1[2], bl1[2];

#define GL_CP(SRC, DOFF) {                                                            \
    gll16((SRC) + wo + (lane << 4), smem + (DOFF) + wo);                              \
    gll16((SRC) + wo + 1024u + (lane << 4), smem + (DOFF) + wo + 1024u); }

#define GL_RA(HALF, DB) { _Pragma("unroll") for (int m = 0; m < 4; ++m) {             \
    uint32_t a = (DB) + swz((uint32_t)(wm * 128 + ((HALF) * 4 + m) * 16 + (lane & 15)), kb); \
    ah[m] = *(const half8*)(smem + a); al[m] = *(const half8*)(smem + a + 16384u); } }

#define GL_RB(NH, DB, BH, BL) { _Pragma("unroll") for (int n = 0; n < 2; ++n) {       \
    uint32_t a = (DB) + 32768u + swz((uint32_t)(wn * 64 + ((NH) * 2 + n) * 16 + (lane & 15)), kb); \
    BH[n] = *(const half8*)(smem + a); BL[n] = *(const half8*)(smem + a + 16384u); } }

#define MFMA_Q(MB, NB, BH, BL) { __builtin_amdgcn_s_setprio(1);                       \
  _Pragma("unroll") for (int m = 0; m < 4; ++m)                                       \
  _Pragma("unroll") for (int n = 0; n < 2; ++n) {                                     \
    float4v* A_ = &acc[(MB) + m][(NB) + n];                                           \
    *A_ = __builtin_amdgcn_mfma_f32_16x16x32_f16(ah[m], BH[n], *A_, 0, 0, 0);         \
    *A_ = __builtin_amdgcn_mfma_f32_16x16x32_f16(ah[m], BL[n], *A_, 0, 0, 0);         \
    *A_ = __builtin_amdgcn_mfma_f32_16x16x32_f16(al[m], BH[n], *A_, 0, 0, 0); }       \
  __builtin_amdgcn_s_setprio(0); }

  // ---- prologue: stage tile 0 into buffer 0 ----
  GL_CP(Ah, 0u); GL_CP(Al, 16384u);
  GL_CP(Bh, 32768u); GL_CP(Bl, 49152u);
  asm volatile("s_waitcnt vmcnt(0)" ::: "memory");
  BAR();

  uint32_t cb = 0u;
  for (int t = 0; t < NT; ++t) {
    const uint32_t nb = cb ^ 65536u;
    const bool st = (t + 1 < NT);
    const uint32_t po = (uint32_t)(t + 1) * BPLANE;
    // P1: ds_read A-half0 + B-half0 ; prefetch A(t+1)
    if (st) { GL_CP(Ah + po, nb); GL_CP(Al + po, nb + 16384u); }
    GL_RA(0, cb);
    GL_RB(0, cb, bh0, bl0);
    BAR();
    MFMA_Q(0, 0, bh0, bl0);
    BAR();
    // P2: ds_read B-half1 ; prefetch B(t+1)
    if (st) { GL_CP(Bh + po, nb + 32768u); GL_CP(Bl + po, nb + 49152u); }
    GL_RB(1, cb, bh1, bl1);
    BAR();
    MFMA_Q(0, 2, bh1, bl1);
    BAR();
    // P3: ds_read A-half1 ; two quadrants ; drain glls (issued >=1 phase ago)
    GL_RA(1, cb);
    BAR();
    MFMA_Q(4, 2, bh1, bl1);
    MFMA_Q(4, 0, bh0, bl0);
    asm volatile("s_waitcnt vmcnt(0)" ::: "memory");
    BAR();
    cb = nb;
  }

  // ---- epilogue: score = c2 - 2*dot ; per-row argmin over this n-tile ----
  u64* scratch = (u64*)smem;
  const int g = lane >> 4;
#pragma unroll
  for (int m = 0; m < 8; ++m) {
#pragma unroll
    for (int r = 0; r < 4; ++r) {
      u64 key = ~0ull;
#pragma unroll
      for (int n = 0; n < 4; ++n) {
        float s = c2v[n] - 2.0f * acc[m][n][r];
        uint32_t ub = __float_as_uint(s);
        ub ^= (uint32_t)((int32_t)ub >> 31) | 0x80000000u;
        u64 cand = ((u64)ub << 32) | (uint32_t)(ncol + n * 16);
        key = cand < key ? cand : key;
      }
#pragma unroll
      for (int d = 1; d < 16; d <<= 1) {
        u64 o = __shfl_xor(key, d, 64);
        key = o < key ? o : key;
      }
      if ((lane & 15) == 0) {
        int row = wm * 128 + m * 16 + g * 4 + r;
        scratch[row * 4 + wn] = key;
      }
    }
  }
  __syncthreads();
  if (tid < 256) {
    u64 k = scratch[tid * 4];
#pragma unroll
    for (int j = 1; j < 4; ++j) { u64 o = scratch[tid * 4 + j]; k = o < k ? o : k; }
    partial[(size_t)(m0 + tid) * NTN + nt] = k;
  }
}

// ================= GEMM variant B: reg-staged (fallback, exact R6) =================
__global__ __launch_bounds__(512, 2) void cluster_gemm_rs(const float* __restrict__ X,
                                                          const uint8_t* __restrict__ wsro,
                                                          u64* __restrict__ partial) {
  extern __shared__ uint8_t smem[];

  const int bid = blockIdx.x;
  const int L = (bid & 7) * 128 + (bid >> 3);
  const int m_tile = L >> 2, n_tile = L & 3;
  const int m0 = m_tile * BM;

  const int tid = threadIdx.x;
  const int lane = tid & 63, w = tid >> 6;
  const int wm = w >> 2, wn = w & 3;
  const uint32_t kb = (uint32_t)((lane >> 4) << 4);

  const float* c2p = (const float*)(wsro + C2_OFF);
  const int ncol = n_tile * 256 + wn * 64 + (lane & 15);
  float c2v[4];
#pragma unroll
  for (int n = 0; n < 4; ++n) c2v[n] = c2p[ncol + n * 16];

  float4v acc[8][4];
#pragma unroll
  for (int m = 0; m < 8; ++m)
#pragma unroll
    for (int n = 0; n < 4; ++n) acc[m][n] = (float4v){0.f, 0.f, 0.f, 0.f};

  float4v apf[4];
  half8 ah[4], al[4], bh0[2], bl0[2], bh1[2], bl1[2];

#define A_LOAD(T1) { const int d0 = (T1) * BK;                                        \
  _Pragma("unroll") for (int i = 0; i < 4; ++i) {                                     \
    int f = tid + i * 512; int row = f >> 3, c4 = f & 7;                              \
    apf[i] = *(const float4v*)(X + (size_t)(m0 + row) * D_DIM + d0 + c4 * 4); } }

#define A_WRITE(DB) { _Pragma("unroll") for (int i = 0; i < 4; ++i) {                 \
    int f = tid + i * 512; int row = f >> 3, c4 = f & 7;                              \
    half4v hi, lo;                                                                    \
    _Pragma("unroll") for (int j = 0; j < 4; ++j) {                                   \
      half_t h = (half_t)apf[i][j]; hi[j] = h; lo[j] = (half_t)(apf[i][j] - (float)h);} \
    uint32_t a = (DB) + swz((uint32_t)row, (uint32_t)c4 * 8u);                        \
    *(half4v*)(smem + a) = hi; *(half4v*)(smem + a + 16384u) = lo; } }

#define B_GLL_HI(T1, DB) { const uint8_t* s_ = wsro + (uint32_t)(n_tile * NT + (T1)) * BPLANE; \
    uint32_t o_ = (uint32_t)w * 2048u;                                                \
    gll16(s_ + o_ + (lane << 4), smem + (DB) + o_);                                   \
    gll16(s_ + o_ + 1024u + (lane << 4), smem + (DB) + o_ + 1024u); }

#define B_GLL_LO(T1, DB) { const uint8_t* s_ = wsro + CLO_OFF + (uint32_t)(n_tile * NT + (T1)) * BPLANE; \
    uint32_t o_ = (uint32_t)w * 2048u;                                                \
    gll16(s_ + o_ + (lane << 4), smem + (DB) + 16384u + o_);                          \
    gll16(s_ + o_ + 1024u + (lane << 4), smem + (DB) + 16384u + o_ + 1024u); }

#define READ_A(HALF, AB) { _Pragma("unroll") for (int m = 0; m < 4; ++m) {            \
    uint32_t a = (AB) + swz((uint32_t)(wm * 128 + ((HALF) * 4 + m) * 16 + (lane & 15)), kb); \
    ah[m] = *(const half8*)(smem + a); al[m] = *(const half8*)(smem + a + 16384u); } }

#define READ_B(NH, BB, BH, BL) { _Pragma("unroll") for (int n = 0; n < 2; ++n) {      \
    uint32_t a = (BB) + swz((uint32_t)(wn * 64 + ((NH) * 2 + n) * 16 + (lane & 15)), kb); \
    BH[n] = *(const half8*)(smem + a); BL[n] = *(const half8*)(smem + a + 16384u); } }

  uint32_t Ab = 0u, Bb = 65536u;

  A_LOAD(0);
  B_GLL_HI(0, Bb); B_GLL_LO(0, Bb);
  A_WRITE(Ab);
  asm volatile("s_waitcnt vmcnt(0) lgkmcnt(0)" ::: "memory");
  BAR();

  for (int t = 0; t < NT; ++t) {
    const uint32_t AbN = Ab ^ 32768u, BbN = Bb ^ 32768u;
    const bool st = (t + 1 < NT);
    if (st) { A_LOAD(t + 1); B_GLL_HI(t + 1, BbN); }
    READ_A(0, Ab);
    READ_B(0, Bb, bh0, bl0);
    BAR();
    MFMA_Q(0, 0, bh0, bl0);
    BAR();
    if (st) { B_GLL_LO(t + 1, BbN); }
    READ_B(1, Bb, bh1, bl1);
    BAR();
    MFMA_Q(0, 2, bh1, bl1);
    BAR();
    READ_A(1, Ab);
    BAR();
    MFMA_Q(4, 2, bh1, bl1);
    BAR();
    if (st) { A_WRITE(AbN); }
    MFMA_Q(4, 0, bh0, bl0);
    asm volatile("s_waitcnt vmcnt(0) lgkmcnt(0)" ::: "memory");
    BAR();
    Ab = AbN; Bb = BbN;
  }

  u64* scratch = (u64*)smem;
  const int g = lane >> 4;
#pragma unroll
  for (int m = 0; m < 8; ++m) {
#pragma unroll
    for (int r = 0; r < 4; ++r) {
      u64 key = ~0ull;
#pragma unroll
      for (int n = 0; n < 4; ++n) {
        float s = c2v[n] - 2.0f * acc[m][n][r];
        uint32_t ub = __float_as_uint(s);
        ub ^= (uint32_t)((int32_t)ub >> 31) | 0x80000000u;
        u64 cand = ((u64)ub << 32) | (uint32_t)(ncol + n * 16);
        key = cand < key ? cand : key;
      }
#pragma unroll
      for (int d = 1; d < 16; d <<= 1) {
        u64 o = __shfl_xor(key, d, 64);
        key = o < key ? o : key;
      }
      if ((lane & 15) == 0) {
        int row = wm * 128 + m * 16 + g * 4 + r;
        scratch[row * 4 + wn] = key;
      }
    }
  }
  __syncthreads();
  if (tid < 256) {
    u64 k = scratch[tid * 4];
#pragma unroll
    for (int j = 1; j < 4; ++j) { u64 o = scratch[tid * 4 + j]; k = o < k ? o : k; }
    partial[(size_t)(m0 + tid) * NTN + n_tile] = k;
  }
}

// ---------------- kernel 3: combine partials -> output ----------------
__global__ __launch_bounds__(256) void finalize(const u64* __restrict__ partial,
                                                const float* __restrict__ gates,
                                                const float* __restrict__ att,
                                                const int* __restrict__ ecp,
                                                float* __restrict__ out) {
  int r = blockIdx.x * 256 + threadIdx.x;
  const u64* p = partial + (size_t)r * NTN;
  u64 k = p[0];
#pragma unroll
  for (int j = 1; j < NTN; ++j) { u64 o = p[j]; k = o < k ? o : k; }
  int idx = (int)(uint32_t)k;
  out[r] = gates[r] * att[r] * ((idx == *ecp) ? 1.0f : 0.0f);
}

extern "C" void kernel_launch(void* const* d_in, const int* in_sizes, int n_in,
                              void* d_out, int out_size, void* d_ws, size_t ws_size,
                              hipStream_t stream) {
  const float* X     = (const float*)d_in[0];
  const float* gates = (const float*)d_in[1];
  const float* att   = (const float*)d_in[2];
  const float* cent  = (const float*)d_in[3];
  const int*   ec    = (const int*)d_in[4];
  uint8_t* ws = (uint8_t*)d_ws;
  float* out = (float*)d_out;
  u64* partial = (u64*)(ws + PART_OFF);

  hipFuncSetAttribute((const void*)cluster_gemm_gl,
                      hipFuncAttributeMaxDynamicSharedMemorySize, 131072);
  hipFuncSetAttribute((const void*)cluster_gemm_rs,
                      hipFuncAttributeMaxDynamicSharedMemorySize, 131072);

  prep_centroids<<<K_CENT, 256, 0, stream>>>(cent, ws);
  if (ws_size >= WS_NEED) {
    prep_x<<<256 * 24, 256, 0, stream>>>(X, ws);
    cluster_gemm_gl<<<(M_TOTAL / BM) * NTN, 512, 131072, stream>>>(ws, partial);
  } else {
    cluster_gemm_rs<<<(M_TOTAL / BM) * NTN, 512, 131072, stream>>>(X, ws, partial);
  }
  finalize<<<M_TOTAL / 256, 256, 0, stream>>>(partial, gates, att, ec, out);
}